// Round 5
// baseline (1188.970 us; speedup 1.0000x reference)
//
#include <hip/hip_runtime.h>
#include <cstddef>

typedef __attribute__((ext_vector_type(8))) short bf16x8;
typedef __attribute__((ext_vector_type(4))) short bf16x4;
typedef __attribute__((ext_vector_type(4))) float f32x4;

constexpr int Bc = 64;
constexpr int Sc = 200;
constexpr int Hc = 4;
constexpr int Dc = 256;
constexpr int HDc = 64;
constexpr int NPc = Bc * Sc;          // 12800 rows
constexpr int NPROJ = 15;
constexpr float SCALE = 0.125f;       // 1/sqrt(64)

// proj indices
// 0 iq, 1 ik, 2 iv, 3 pq, 4 pk, 5 aq, 6 ak, 7 haq, 8 hak, 9 hav,
// 10 iqc, 11 ciq, 12 cqp, 13 cqp_a, 14 pqc

__constant__ int c_KP9[3]  = {1,6,4};                   // K proj per group
__constant__ int c_QP9[9]  = {0,11,3, 10,5,14, 0,12,3}; // Q proj per (g,k) slot
__constant__ int c_CG9[9]  = {0,3,6, 1,4,7, 2,5,8};     // slot -> channel
__constant__ int c_M2S9[9] = {0,24,48,8,32,56,16,40,64};// channel -> S row base
__constant__ int c_KP4[2]  = {8,4};
__constant__ int c_QP4[4]  = {7,14, 13,3};
__constant__ int c_CG4[4]  = {0,2, 1,3};
__constant__ int c_M2S4[4] = {0,16,8,24};

__device__ __forceinline__ short f2bf(float x) {
    union { float f; unsigned u; } v; v.f = x;
    unsigned r = v.u + 0x7FFFu + ((v.u >> 16) & 1u);
    return (short)(r >> 16);
}
__device__ __forceinline__ float bf2f(short x) {
    union { unsigned u; float f; } v; v.u = ((unsigned)(unsigned short)x) << 16;
    return v.f;
}
__device__ __forceinline__ f32x4 mfma16(bf16x8 a, bf16x8 b, f32x4 c) {
    return __builtin_amdgcn_mfma_f32_16x16x32_bf16(a, b, c, 0, 0, 0);
}

struct ProjArgsM {
    const short* A[NPROJ];      // bf16 input per projection
    const float* bias[NPROJ];
    float*       outf[NPROJ];   // fp32 output (V tensors only)
};
struct WList { const float* w[NPROJ]; };

// ---------------------------------------------------------------------------
// cast 4 input tensors fp32 -> bf16
// grid (NPc*Dc/4/256, 4)
// ---------------------------------------------------------------------------
__global__ void cast_in(const float* __restrict__ s0, const float* __restrict__ s1,
                        const float* __restrict__ s2, const float* __restrict__ s3,
                        short* __restrict__ dst) {
    const float* srcs[4] = {s0, s1, s2, s3};
    const float* src = srcs[blockIdx.y];
    short* d = dst + (size_t)blockIdx.y * NPc * Dc;
    int t = blockIdx.x * 256 + threadIdx.x;
    float4 v = ((const float4*)src)[t];
    bf16x4 o;
    o[0] = f2bf(v.x); o[1] = f2bf(v.y); o[2] = f2bf(v.z); o[3] = f2bf(v.w);
    *(bf16x4*)(d + (size_t)t * 4) = o;
}

// ---------------------------------------------------------------------------
// cast+transpose 15 weights: WT[p][n][k] = W[p][k][n]  (bf16)
// grid (16, 15): 64x64 tiles
// ---------------------------------------------------------------------------
__global__ void cast_wt(WList wl, short* __restrict__ dst) {
    __shared__ float tbuf[64][65];
    const int p = blockIdx.y;
    const int k0 = (blockIdx.x >> 2) * 64, n0 = (blockIdx.x & 3) * 64;
    const float* W = wl.w[p];
    short* d = dst + (size_t)p * Dc * Dc;
    const int tid = threadIdx.x;
    for (int i = tid; i < 64 * 64; i += 256) {
        int k = i >> 6, n = i & 63;
        tbuf[k][n] = W[(size_t)(k0 + k) * Dc + n0 + n];
    }
    __syncthreads();
    for (int i = tid; i < 64 * 64; i += 256) {
        int n = i >> 6, k = i & 63;
        d[(size_t)(n0 + n) * Dc + k0 + k] = f2bf(tbuf[k][n]);
    }
}

// ---------------------------------------------------------------------------
// Wf1 (200x200 f32) -> WT bf16 [224][224], WT[j][i] = Wf1[i][j], 0-pad
// ---------------------------------------------------------------------------
__global__ void wf1t_kernel(const float* __restrict__ Wf1, short* __restrict__ WT) {
    int t = blockIdx.x * 256 + threadIdx.x;
    if (t < 224 * 224) {
        int j = t / 224, i = t % 224;
        WT[t] = (i < Sc && j < Sc) ? f2bf(Wf1[(size_t)i * Sc + j]) : (short)0;
    }
}

// ---------------------------------------------------------------------------
// Kernel 1 (MFMA): all 15 projections. C[64 x 256] tile per block.
// grid (200, 15), 256 threads (4 waves, one 64-col strip each)
// ---------------------------------------------------------------------------
__global__ __launch_bounds__(256, 4) void proj_mfma(
    ProjArgsM args, const short* __restrict__ WTall, short* __restrict__ proj_bf)
{
    const int p  = blockIdx.y;
    const int m0 = blockIdx.x * 64;
    const short* __restrict__ A   = args.A[p];
    const short* __restrict__ WTp = WTall + (size_t)p * Dc * Dc;
    const float* __restrict__ bias = args.bias[p];
    float* __restrict__ of = args.outf[p];
    short* __restrict__ ob = proj_bf + (size_t)p * NPc * Dc;

    __shared__ __align__(16) short As[64 * 264];
    const int tid = threadIdx.x;
    const int lane = tid & 63, w = tid >> 6;
    const int l15 = lane & 15, l4 = lane >> 4;

    for (int t = tid; t < 64 * 32; t += 256) {
        int r = t >> 5, c8 = t & 31;
        *(bf16x8*)(As + r * 264 + c8 * 8) = *(const bf16x8*)(A + (size_t)(m0 + r) * Dc + c8 * 8);
    }
    __syncthreads();

    f32x4 acc[4][4];
    #pragma unroll
    for (int mi = 0; mi < 4; ++mi)
        #pragma unroll
        for (int ni = 0; ni < 4; ++ni) acc[mi][ni] = (f32x4){};

    const int nb = w * 64;
    #pragma unroll
    for (int ks = 0; ks < 8; ++ks) {
        bf16x8 bfr[4];
        #pragma unroll
        for (int ni = 0; ni < 4; ++ni)
            bfr[ni] = *(const bf16x8*)(WTp + (size_t)(nb + ni * 16 + l15) * Dc + ks * 32 + l4 * 8);
        #pragma unroll
        for (int mi = 0; mi < 4; ++mi) {
            bf16x8 a = *(const bf16x8*)(As + (mi * 16 + l15) * 264 + ks * 32 + l4 * 8);
            #pragma unroll
            for (int ni = 0; ni < 4; ++ni)
                acc[mi][ni] = mfma16(a, bfr[ni], acc[mi][ni]);
        }
    }

    float bv[4];
    #pragma unroll
    for (int ni = 0; ni < 4; ++ni) bv[ni] = bias[nb + ni * 16 + l15];
    #pragma unroll
    for (int mi = 0; mi < 4; ++mi) {
        #pragma unroll
        for (int ni = 0; ni < 4; ++ni) {
            int n = nb + ni * 16 + l15;
            #pragma unroll
            for (int i = 0; i < 4; ++i) {
                int m = m0 + mi * 16 + l4 * 4 + i;
                float v = acc[mi][ni][i] + bv[ni];
                ob[(size_t)m * Dc + n] = f2bf(v);
                if (of) of[(size_t)m * Dc + n] = v;
            }
        }
    }
}

// ---------------------------------------------------------------------------
// fused body (R = 8 rows per block, 8 waves)
// ---------------------------------------------------------------------------
template <int CH, int NG, int CPG, int QT, int MT2>
__device__ void fused_body(
    int bid,
    const short* __restrict__ proj_bf,
    const float* __restrict__ vf32,
    const float* __restrict__ fw,
    const float* __restrict__ mask,
    const short* __restrict__ WT,
    const float* __restrict__ bf1,
    const float* __restrict__ Wf2,
    float* __restrict__ ctx_out,
    const int* KP, const int* QP, const int* CG, const int* M2S,
    short* Sl, float* gbuf, float* evw, float* wch, float* fwl,
    float* bf1l, float* wf2l, float* part)
{
    constexpr int GR    = CPG * 8;     // valid S rows per group
    constexpr int SROWS = MT2 * 16;
    constexpr int SLD   = 232;
    constexpr int R     = 8;
    constexpr int NW    = 8;

    const int tid = threadIdx.x;
    const int rt  = bid % 25;
    const int h   = (bid / 25) & 3;
    const int b   = bid / 100;
    const int r0  = rt * 8;
    const int lane = tid & 63, wv = tid >> 6;   // wv 0..7
    const int l15 = lane & 15, l4 = lane >> 4;
    const int brow0 = b * Sc + r0;

    // ---- phase 0: zero Sl; stage bf1/Wf2 (0-padded); fw
    {
        bf16x8 z = {};
        for (int t = tid; t < SROWS * SLD / 8; t += 512) ((bf16x8*)Sl)[t] = z;
    }
    if (tid < 224) {
        bf1l[tid] = (tid < Sc) ? bf1[tid] : 0.f;
        wf2l[tid] = (tid < Sc) ? Wf2[tid] : 0.f;
    }
    if (tid < CH) fwl[tid] = fw[tid];

    // ---- preload Q A-fragments from global (registers, per wave)
    bf16x8 af[NG][QT][2];
    #pragma unroll
    for (int g = 0; g < NG; ++g) {
        #pragma unroll
        for (int t = 0; t < QT; ++t) {
            int sr = t * 16 + l15;
            int kk = (sr < GR) ? (sr >> 3) : 0;
            int rr = (sr < GR) ? (sr & 7) : 0;
            const short* qp = proj_bf + ((size_t)QP[g * CPG + kk] * NPc + brow0 + rr) * Dc + h * HDc;
            #pragma unroll
            for (int ks = 0; ks < 2; ++ks)
                af[g][t][ks] = *(const bf16x8*)(qp + ks * 32 + l4 * 8);
        }
    }
    __syncthreads();

    // ---- scores: S[m][j] = fw[c] * (q_m . k_j)  (MFMA, bf16 out to Sl)
    for (int nt = wv; nt < 13; nt += NW) {
        int j = nt * 16 + l15;
        bf16x8 bfr[NG][2];
        #pragma unroll
        for (int g = 0; g < NG; ++g) {
            const short* Kb = proj_bf + ((size_t)KP[g] * NPc + (size_t)b * Sc) * Dc + h * HDc;
            #pragma unroll
            for (int ks = 0; ks < 2; ++ks)
                bfr[g][ks] = *(const bf16x8*)(Kb + (size_t)j * Dc + ks * 32 + l4 * 8);
        }
        #pragma unroll
        for (int g = 0; g < NG; ++g) {
            #pragma unroll
            for (int t = 0; t < QT; ++t) {
                f32x4 c = {};
                c = mfma16(af[g][t][0], bfr[g][0], c);
                c = mfma16(af[g][t][1], bfr[g][1], c);
                int k = t * 2 + (l4 >> 1);
                if (j < Sc && k < CPG) {
                    float f = fwl[CG[g * CPG + k]];
                    int srb = t * 16 + l4 * 4;
                    #pragma unroll
                    for (int i = 0; i < 4; ++i)
                        Sl[(g * GR + srb + i) * SLD + j] = f2bf(c[i] * f);
                }
            }
        }
    }
    __syncthreads();

    // ---- gate (swapped): C[j][m] = sum_i WT[j][i] * S[m][i]; e[m] reduce
    {
        float epart[MT2];
        #pragma unroll
        for (int mt = 0; mt < MT2; ++mt) epart[mt] = 0.f;

        for (int nt = wv; nt < 13; nt += NW) {
            int jr = nt * 16 + l15;
            float4 b1 = *(const float4*)(bf1l + nt * 16 + l4 * 4);
            float4 w2 = *(const float4*)(wf2l + nt * 16 + l4 * 4);
            f32x4 cg[MT2];
            #pragma unroll
            for (int mt = 0; mt < MT2; ++mt) cg[mt] = (f32x4){};
            #pragma unroll
            for (int ks = 0; ks < 7; ++ks) {
                bf16x8 aa = *(const bf16x8*)(WT + (size_t)jr * 224 + ks * 32 + l4 * 8);
                #pragma unroll
                for (int mt = 0; mt < MT2; ++mt) {
                    bf16x8 bb = *(const bf16x8*)(Sl + (mt * 16 + l15) * SLD + ks * 32 + l4 * 8);
                    cg[mt] = mfma16(aa, bb, cg[mt]);
                }
            }
            #pragma unroll
            for (int mt = 0; mt < MT2; ++mt) {
                float s = fmaxf(cg[mt][0] + b1.x, 0.f) * w2.x
                        + fmaxf(cg[mt][1] + b1.y, 0.f) * w2.y
                        + fmaxf(cg[mt][2] + b1.z, 0.f) * w2.z
                        + fmaxf(cg[mt][3] + b1.w, 0.f) * w2.w;
                s += __shfl_xor(s, 16, 64);
                s += __shfl_xor(s, 32, 64);
                epart[mt] += s;
            }
        }
        if (l4 == 0) {
            #pragma unroll
            for (int mt = 0; mt < MT2; ++mt)
                evw[wv * SROWS + mt * 16 + l15] = epart[mt];
        }
    }
    __syncthreads();

    // ---- channel softmax per row
    if (tid < R) {
        int r = tid;
        float e[CH]; float mx = -1e30f;
        #pragma unroll
        for (int c = 0; c < CH; ++c) {
            int m = M2S[c] + r;
            float s = 0.f;
            #pragma unroll
            for (int w = 0; w < NW; ++w) s += evw[w * SROWS + m];
            e[c] = s; mx = fmaxf(mx, s);
        }
        float sum = 0.f;
        #pragma unroll
        for (int c = 0; c < CH; ++c) { e[c] = __expf(e[c] - mx); sum += e[c]; }
        float inv = 1.f / sum;
        #pragma unroll
        for (int c = 0; c < CH; ++c) wch[M2S[c] + r] = e[c] * inv;
    }
    __syncthreads();

    // ---- gated sum + scale + mask -> gbuf (fp32)
    for (int idx = tid; idx < R * Sc; idx += 512) {
        int r = idx / Sc, j = idx - r * Sc;
        float acc = 0.f;
        #pragma unroll
        for (int c = 0; c < CH; ++c) {
            int m = M2S[c] + r;
            acc += wch[m] * bf2f(Sl[m * SLD + j]);
        }
        gbuf[r * 200 + j] = acc * SCALE + mask[((size_t)b * Sc + r0 + r) * Sc + j];
    }
    __syncthreads();

    // ---- row softmax: wave wv owns row wv
    {
        const int r = wv;
        float vals[4]; float mpart = -1e30f;
        #pragma unroll
        for (int t4 = 0; t4 < 4; ++t4) {
            int j = t4 * 64 + lane;
            vals[t4] = (j < Sc) ? gbuf[r * 200 + j] : -1e30f;
            mpart = fmaxf(mpart, vals[t4]);
        }
        #pragma unroll
        for (int off = 32; off >= 1; off >>= 1) mpart = fmaxf(mpart, __shfl_xor(mpart, off, 64));
        float spart = 0.f;
        #pragma unroll
        for (int t4 = 0; t4 < 4; ++t4) {
            int j = t4 * 64 + lane;
            if (j < Sc) {
                float exv = __expf(vals[t4] - mpart);
                gbuf[r * 200 + j] = exv;
                spart += exv;
            }
        }
        #pragma unroll
        for (int off = 32; off >= 1; off >>= 1) spart += __shfl_xor(spart, off, 64);
        float inv = 1.f / spart;
        #pragma unroll
        for (int t4 = 0; t4 < 4; ++t4) {
            int j = t4 * 64 + lane;
            if (j < Sc) gbuf[r * 200 + j] *= inv;
        }
    }
    __syncthreads();

    // ---- PV: wave w handles rows {w&3, (w&3)+4} over j-half (w>>2)
    {
        const int half = wv >> 2;
        const int ra = wv & 3, rb = ra + 4;
        const int j0 = half * 100;
        const float* vb = vf32 + ((size_t)b * Sc) * Dc + h * HDc + lane;
        const float* pA = gbuf + ra * 200;
        const float* pB = gbuf + rb * 200;
        float aA0 = 0.f, aA1 = 0.f, aA2 = 0.f, aA3 = 0.f;
        float aB0 = 0.f, aB1 = 0.f, aB2 = 0.f, aB3 = 0.f;
        for (int j = j0; j < j0 + 100; j += 4) {
            float v0 = vb[(size_t)(j + 0) * Dc];
            float v1 = vb[(size_t)(j + 1) * Dc];
            float v2 = vb[(size_t)(j + 2) * Dc];
            float v3 = vb[(size_t)(j + 3) * Dc];
            aA0 += pA[j] * v0; aA1 += pA[j + 1] * v1; aA2 += pA[j + 2] * v2; aA3 += pA[j + 3] * v3;
            aB0 += pB[j] * v0; aB1 += pB[j + 1] * v1; aB2 += pB[j + 2] * v2; aB3 += pB[j + 3] * v3;
        }
        part[(half * R + ra) * 64 + lane] = aA0 + aA1 + aA2 + aA3;
        part[(half * R + rb) * 64 + lane] = aB0 + aB1 + aB2 + aB3;
    }
    __syncthreads();
    {
        const int r = tid >> 6, d = lane;   // 8 rows x 64 d = 512 threads
        float v = part[r * 64 + d] + part[(R + r) * 64 + d];
        ctx_out[((size_t)(brow0 + r)) * Dc + h * HDc + d] = v;
    }
}

// ---------------------------------------------------------------------------
// Kernel 2 (v5): merged fused attention, 512 threads
// grid = 6400 (9ch) + 6400 (4ch)
// ---------------------------------------------------------------------------
__global__ __launch_bounds__(512, 6) void fused5(
    const short* __restrict__ proj_bf,
    const float* __restrict__ viv,
    const float* __restrict__ vhav,
    const float* __restrict__ fw9,
    const float* __restrict__ fw4,
    const float* __restrict__ mask,
    const short* __restrict__ WT,
    const float* __restrict__ bf1,
    const float* __restrict__ Wf2,
    float* __restrict__ ctx,
    float* __restrict__ ctxc)
{
    __shared__ __align__(16) short Sl[80 * 232];
    __shared__ float gbuf[8 * 200];
    __shared__ float evw[8 * 80];
    __shared__ float wch[80];
    __shared__ float fwl[9];
    __shared__ float bf1l[224];
    __shared__ float wf2l[224];
    __shared__ float part[2 * 8 * 64];

    const int bid = blockIdx.x;
    if (bid < 6400) {
        fused_body<9, 3, 3, 2, 5>(bid, proj_bf, viv, fw9, mask, WT, bf1, Wf2, ctx,
                                  c_KP9, c_QP9, c_CG9, c_M2S9,
                                  Sl, gbuf, evw, wch, fwl, bf1l, wf2l, part);
    } else {
        fused_body<4, 2, 2, 1, 2>(bid - 6400, proj_bf, vhav, fw4, mask, WT, bf1, Wf2, ctxc,
                                  c_KP4, c_QP4, c_CG4, c_M2S4,
                                  Sl, gbuf, evw, wch, fwl, bf1l, wf2l, part);
    }
}

// ---------------------------------------------------------------------------
// Kernel 3: out = LayerNorm( A @ W + bias + resid ) * gamma + beta
// ---------------------------------------------------------------------------
__global__ __launch_bounds__(256) void out_ln_kernel(
    const float* __restrict__ Actx,
    const float* __restrict__ W,
    const float* __restrict__ bias,
    const float* __restrict__ resid,
    const float* __restrict__ gamma,
    const float* __restrict__ beta,
    float* __restrict__ out)
{
    const int m0 = blockIdx.x * 16;
    const int tid = threadIdx.x;

    __shared__ float As[16][256];
    __shared__ float ylds[16][256];

    for (int t = tid; t < 16 * 64; t += 256) {
        int r = t >> 6, k4 = t & 63;
        ((float4*)As[r])[k4] = ((const float4*)(Actx + (size_t)(m0 + r) * Dc))[k4];
    }
    __syncthreads();

    float acc[16];
    #pragma unroll
    for (int r = 0; r < 16; r++) acc[r] = 0.f;

    for (int k = 0; k < 256; k += 4) {
        float w0 = W[(size_t)(k    ) * Dc + tid];
        float w1 = W[(size_t)(k + 1) * Dc + tid];
        float w2 = W[(size_t)(k + 2) * Dc + tid];
        float w3 = W[(size_t)(k + 3) * Dc + tid];
        #pragma unroll
        for (int r = 0; r < 16; r++) {
            float4 a4 = ((float4*)As[r])[k >> 2];
            acc[r] += a4.x * w0 + a4.y * w1 + a4.z * w2 + a4.w * w3;
        }
    }

    const float bv = bias[tid];
    #pragma unroll
    for (int r = 0; r < 16; r++) {
        ylds[r][tid] = acc[r] + bv + resid[(size_t)(m0 + r) * Dc + tid];
    }
    __syncthreads();

    const int lane = tid & 63;
    const int wv   = tid >> 6;
    for (int r = wv * 4; r < wv * 4 + 4; r++) {
        float v4[4];
        float s = 0.f, s2 = 0.f;
        #pragma unroll
        for (int t4 = 0; t4 < 4; t4++) {
            float v = ylds[r][t4 * 64 + lane];
            v4[t4] = v;
            s += v;
            s2 += v * v;
        }
        #pragma unroll
        for (int off = 32; off >= 1; off >>= 1) {
            s  += __shfl_xor(s, off, 64);
            s2 += __shfl_xor(s2, off, 64);
        }
        float m   = s * (1.f / 256.f);
        float var = s2 * (1.f / 256.f) - m * m;
        float rstd = rsqrtf(var + 1e-12f);
        #pragma unroll
        for (int t4 = 0; t4 < 4; t4++) {
            int ccol = t4 * 64 + lane;
            out[(size_t)(m0 + r) * Dc + ccol] = (v4[t4] - m) * rstd * gamma[ccol] + beta[ccol];
        }
    }
}

// ---------------------------------------------------------------------------
// Launcher
// ---------------------------------------------------------------------------
extern "C" void kernel_launch(void* const* d_in, const int* in_sizes, int n_in,
                              void* d_out, int out_size, void* d_ws, size_t ws_size,
                              hipStream_t stream) {
    const float* X    = (const float*)d_in[0];
    const float* AT   = (const float*)d_in[1];
    const float* P    = (const float*)d_in[2];
    const float* HA   = (const float*)d_in[3];
    const float* mask = (const float*)d_in[4];
    const float* fw   = (const float*)d_in[5];
    const float* fwc  = (const float*)d_in[6];

    const float* Wq   = (const float*)d_in[7];
    const float* bq   = (const float*)d_in[8];
    const float* Wk   = (const float*)d_in[9];
    const float* bk   = (const float*)d_in[10];
    const float* Wv   = (const float*)d_in[11];
    const float* bv   = (const float*)d_in[12];
    const float* Wqp  = (const float*)d_in[13];
    const float* bqp  = (const float*)d_in[14];
    const float* Wkp  = (const float*)d_in[15];
    const float* bkp  = (const float*)d_in[16];
    const float* Waq  = (const float*)d_in[17];
    const float* baq  = (const float*)d_in[18];
    const float* Wak  = (const float*)d_in[19];
    const float* bak  = (const float*)d_in[20];
    const float* Wav  = (const float*)d_in[21];
    const float* bav  = (const float*)d_in[22];
    const float* Wqic = (const float*)d_in[23];
    const float* bqic = (const float*)d_in[24];
    const float* Wqci = (const float*)d_in[25];
    const float* bqci = (const float*)d_in[26];
    const float* Wqpc = (const float*)d_in[27];
    const float* bqpc = (const float*)d_in[28];
    const float* Wqcp = (const float*)d_in[29];
    const float* bqcp = (const float*)d_in[30];
    const float* Wf1  = (const float*)d_in[31];
    const float* bf1  = (const float*)d_in[32];
    const float* Wf2  = (const float*)d_in[33];
    const float* bf2  = (const float*)d_in[34];
    const float* Wd   = (const float*)d_in[35];
    const float* bd   = (const float*)d_in[36];
    const float* ln_g = (const float*)d_in[37];
    const float* ln_b = (const float*)d_in[38];
    const float* Wda  = (const float*)d_in[39];
    const float* bda  = (const float*)d_in[40];
    const float* lna_g= (const float*)d_in[41];
    const float* lna_b= (const float*)d_in[42];

    char* w = (char*)d_ws;
    short* proj_bf = (short*)w;  w += (size_t)NPROJ * NPc * Dc * sizeof(short);
    short* WTall   = (short*)w;  w += (size_t)NPROJ * Dc * Dc * sizeof(short);
    short* WTf1    = (short*)w;  w += (size_t)224 * 224 * sizeof(short);
    short* inb     = (short*)w;  w += (size_t)4 * NPc * Dc * sizeof(short);
    float* viv     = (float*)w;  w += (size_t)NPc * Dc * sizeof(float);
    float* vhav    = (float*)w;  w += (size_t)NPc * Dc * sizeof(float);
    float* ctx     = (float*)w;  w += (size_t)NPc * Dc * sizeof(float);
    float* ctxc    = (float*)w;  w += (size_t)NPc * Dc * sizeof(float);

    // input-tensor id per projection: 0=X 1=AT 2=P 3=HA
    const int aid[NPROJ] = {0,0,0,2,2,1,1,3,3,3,0,1,1,3,2};
    const float* Wmat[NPROJ] = {Wq, Wk, Wv, Wqp, Wkp, Waq, Wak, Waq, Wak, Wav, Wqic, Wqci, Wqcp, Wqcp, Wqpc};
    const float* bmat[NPROJ] = {bq, bk, bv, bqp, bkp, baq, bak, baq, bak, bav, bqic, bqci, bqcp, bqcp, bqpc};

    ProjArgsM pm;
    WList wl;
    for (int i = 0; i < NPROJ; i++) {
        pm.A[i]    = inb + (size_t)aid[i] * NPc * Dc;
        pm.bias[i] = bmat[i];
        pm.outf[i] = nullptr;
        wl.w[i]    = Wmat[i];
    }
    pm.outf[2] = viv;    // iv
    pm.outf[9] = vhav;   // hav

    // 0. casts
    cast_in<<<dim3(NPc * Dc / 4 / 256, 4), 256, 0, stream>>>(X, AT, P, HA, inb);
    cast_wt<<<dim3(16, NPROJ), 256, 0, stream>>>(wl, WTall);
    wf1t_kernel<<<(224 * 224 + 255) / 256, 256, 0, stream>>>(Wf1, WTf1);

    // 1. projections (MFMA, bf16 in/out + fp32 for V)
    proj_mfma<<<dim3(NPc / 64, NPROJ), 256, 0, stream>>>(pm, WTall, proj_bf);

    // 2. merged fused attention
    fused5<<<12800, 512, 0, stream>>>(proj_bf, viv, vhav, fw, fwc, mask, WTf1, bf1, Wf2, ctx, ctxc);

    // 3. output projections + residual + LayerNorm
    float* out0 = (float*)d_out;
    float* out1 = out0 + (size_t)NPc * Dc;
    out_ln_kernel<<<NPc / 16, 256, 0, stream>>>(ctx,  Wd,  bd,  X,  ln_g,  ln_b,  out0);
    out_ln_kernel<<<NPc / 16, 256, 0, stream>>>(ctxc, Wda, bda, HA, lna_g, lna_b, out1);
}

// Round 6
// 587.906 us; speedup vs baseline: 2.0224x; 2.0224x over previous
//
#include <hip/hip_runtime.h>
#include <cstddef>

typedef __attribute__((ext_vector_type(8))) short bf16x8;
typedef __attribute__((ext_vector_type(4))) short bf16x4;
typedef __attribute__((ext_vector_type(4))) float f32x4;

constexpr int Bc = 64;
constexpr int Sc = 200;
constexpr int Hc = 4;
constexpr int Dc = 256;
constexpr int HDc = 64;
constexpr int NPc = Bc * Sc;          // 12800 rows
constexpr int NPROJ = 15;
constexpr float SCALE = 0.125f;       // 1/sqrt(64)

// proj indices
// 0 iq, 1 ik, 2 iv, 3 pq, 4 pk, 5 aq, 6 ak, 7 haq, 8 hak, 9 hav,
// 10 iqc, 11 ciq, 12 cqp, 13 cqp_a, 14 pqc

__constant__ int c_KP9[3]  = {1,6,4};                   // K proj per group
__constant__ int c_QP9[9]  = {0,11,3, 10,5,14, 0,12,3}; // Q proj per (g,k) slot
__constant__ int c_CG9[9]  = {0,3,6, 1,4,7, 2,5,8};     // slot -> channel
__constant__ int c_M2S9[9] = {0,24,48,8,32,56,16,40,64};// channel -> S row base
__constant__ int c_KP4[2]  = {8,4};
__constant__ int c_QP4[4]  = {7,14, 13,3};
__constant__ int c_CG4[4]  = {0,2, 1,3};
__constant__ int c_M2S4[4] = {0,16,8,24};

__device__ __forceinline__ short f2bf(float x) {
    union { float f; unsigned u; } v; v.f = x;
    unsigned r = v.u + 0x7FFFu + ((v.u >> 16) & 1u);
    return (short)(r >> 16);
}
__device__ __forceinline__ float bf2f(short x) {
    union { unsigned u; float f; } v; v.u = ((unsigned)(unsigned short)x) << 16;
    return v.f;
}
__device__ __forceinline__ f32x4 mfma16(bf16x8 a, bf16x8 b, f32x4 c) {
    return __builtin_amdgcn_mfma_f32_16x16x32_bf16(a, b, c, 0, 0, 0);
}

struct ProjArgsM {
    const short* A[NPROJ];      // bf16 input per projection
    const float* bias[NPROJ];
    float*       outf[NPROJ];   // fp32 output (V tensors only)
};
struct WList { const float* w[NPROJ]; };

// ---------------------------------------------------------------------------
// cast 4 input tensors fp32 -> bf16
// ---------------------------------------------------------------------------
__global__ void cast_in(const float* __restrict__ s0, const float* __restrict__ s1,
                        const float* __restrict__ s2, const float* __restrict__ s3,
                        short* __restrict__ dst) {
    const float* srcs[4] = {s0, s1, s2, s3};
    const float* src = srcs[blockIdx.y];
    short* d = dst + (size_t)blockIdx.y * NPc * Dc;
    int t = blockIdx.x * 256 + threadIdx.x;
    float4 v = ((const float4*)src)[t];
    bf16x4 o;
    o[0] = f2bf(v.x); o[1] = f2bf(v.y); o[2] = f2bf(v.z); o[3] = f2bf(v.w);
    *(bf16x4*)(d + (size_t)t * 4) = o;
}

// ---------------------------------------------------------------------------
// cast+transpose 15 weights: WT[p][n][k] = W[p][k][n]  (bf16)
// ---------------------------------------------------------------------------
__global__ void cast_wt(WList wl, short* __restrict__ dst) {
    __shared__ float tbuf[64][65];
    const int p = blockIdx.y;
    const int k0 = (blockIdx.x >> 2) * 64, n0 = (blockIdx.x & 3) * 64;
    const float* W = wl.w[p];
    short* d = dst + (size_t)p * Dc * Dc;
    const int tid = threadIdx.x;
    for (int i = tid; i < 64 * 64; i += 256) {
        int k = i >> 6, n = i & 63;
        tbuf[k][n] = W[(size_t)(k0 + k) * Dc + n0 + n];
    }
    __syncthreads();
    for (int i = tid; i < 64 * 64; i += 256) {
        int n = i >> 6, k = i & 63;
        d[(size_t)(n0 + n) * Dc + k0 + k] = f2bf(tbuf[k][n]);
    }
}

// ---------------------------------------------------------------------------
// Wf1 (200x200 f32) -> WT bf16 [224][224], WT[j][i] = Wf1[i][j], 0-pad
// ---------------------------------------------------------------------------
__global__ void wf1t_kernel(const float* __restrict__ Wf1, short* __restrict__ WT) {
    int t = blockIdx.x * 256 + threadIdx.x;
    if (t < 224 * 224) {
        int j = t / 224, i = t % 224;
        WT[t] = (i < Sc && j < Sc) ? f2bf(Wf1[(size_t)i * Sc + j]) : (short)0;
    }
}

// ---------------------------------------------------------------------------
// Kernel 1 (MFMA): all 15 projections. C[64 x 256] tile per block.
// ---------------------------------------------------------------------------
__global__ __launch_bounds__(256, 4) void proj_mfma(
    ProjArgsM args, const short* __restrict__ WTall, short* __restrict__ proj_bf)
{
    const int p  = blockIdx.y;
    const int m0 = blockIdx.x * 64;
    const short* __restrict__ A   = args.A[p];
    const short* __restrict__ WTp = WTall + (size_t)p * Dc * Dc;
    const float* __restrict__ bias = args.bias[p];
    float* __restrict__ of = args.outf[p];
    short* __restrict__ ob = proj_bf + (size_t)p * NPc * Dc;

    __shared__ __align__(16) short As[64 * 264];
    const int tid = threadIdx.x;
    const int lane = tid & 63, w = tid >> 6;
    const int l15 = lane & 15, l4 = lane >> 4;

    for (int t = tid; t < 64 * 32; t += 256) {
        int r = t >> 5, c8 = t & 31;
        *(bf16x8*)(As + r * 264 + c8 * 8) = *(const bf16x8*)(A + (size_t)(m0 + r) * Dc + c8 * 8);
    }
    __syncthreads();

    f32x4 acc[4][4];
    #pragma unroll
    for (int mi = 0; mi < 4; ++mi)
        #pragma unroll
        for (int ni = 0; ni < 4; ++ni) acc[mi][ni] = (f32x4){};

    const int nb = w * 64;
    #pragma unroll
    for (int ks = 0; ks < 8; ++ks) {
        bf16x8 bfr[4];
        #pragma unroll
        for (int ni = 0; ni < 4; ++ni)
            bfr[ni] = *(const bf16x8*)(WTp + (size_t)(nb + ni * 16 + l15) * Dc + ks * 32 + l4 * 8);
        #pragma unroll
        for (int mi = 0; mi < 4; ++mi) {
            bf16x8 a = *(const bf16x8*)(As + (mi * 16 + l15) * 264 + ks * 32 + l4 * 8);
            #pragma unroll
            for (int ni = 0; ni < 4; ++ni)
                acc[mi][ni] = mfma16(a, bfr[ni], acc[mi][ni]);
        }
    }

    float bv[4];
    #pragma unroll
    for (int ni = 0; ni < 4; ++ni) bv[ni] = bias[nb + ni * 16 + l15];
    #pragma unroll
    for (int mi = 0; mi < 4; ++mi) {
        #pragma unroll
        for (int ni = 0; ni < 4; ++ni) {
            int n = nb + ni * 16 + l15;
            #pragma unroll
            for (int i = 0; i < 4; ++i) {
                int m = m0 + mi * 16 + l4 * 4 + i;
                float v = acc[mi][ni][i] + bv[ni];
                ob[(size_t)m * Dc + n] = f2bf(v);
                if (of) of[(size_t)m * Dc + n] = v;
            }
        }
    }
}

// ---------------------------------------------------------------------------
// fused body v6 (R = 8 rows per block, 4 waves, wave-local tail)
// ---------------------------------------------------------------------------
template <int CH, int NG, int CPG, int QT, int MT2>
__device__ void fused_body(
    int bid,
    const short* __restrict__ proj_bf,
    const float* __restrict__ vf32,
    const float* __restrict__ fw,
    const float* __restrict__ mask,
    const short* __restrict__ WT,
    const float* __restrict__ bf1,
    const float* __restrict__ Wf2,
    float* __restrict__ ctx_out,
    const int* KP, const int* QP, const int* CG, const int* M2S,
    short* Sl, float* gbuf, float* evw, float* fwl,
    float* bf1l, float* wf2l)
{
    constexpr int GR    = CPG * 8;       // valid S rows per group
    constexpr int VROWS = NG * GR;       // total valid S rows
    constexpr int SROWS = MT2 * 16;
    constexpr int SLD   = 232;
    constexpr int NW    = 4;

    const int tid = threadIdx.x;
    const int rt  = bid % 25;
    const int h   = (bid / 25) & 3;
    const int b   = bid / 100;
    const int r0  = rt * 8;
    const int lane = tid & 63, wv = tid >> 6;   // wv 0..3
    const int l15 = lane & 15, l4 = lane >> 4;
    const int brow0 = b * Sc + r0;

    // ---- phase 0: zero only pad regions of Sl; stage bf1/Wf2; fw
    {
        bf16x8 z = {};
        if constexpr (SROWS > VROWS) {
            for (int t = tid; t < (SROWS - VROWS) * 28; t += 256) {
                int r = VROWS + t / 28, c8 = t % 28;
                *(bf16x8*)(Sl + r * SLD + c8 * 8) = z;
            }
        }
        for (int t = tid; t < VROWS * 3; t += 256) {
            int r = t / 3, c8 = t % 3;
            *(bf16x8*)(Sl + r * SLD + 200 + c8 * 8) = z;
        }
    }
    if (tid < 224) {
        bf1l[tid] = (tid < Sc) ? bf1[tid] : 0.f;
        wf2l[tid] = (tid < Sc) ? Wf2[tid] : 0.f;
    }
    if (tid < CH) fwl[tid] = fw[tid];

    // ---- preload Q A-fragments from global (registers)
    bf16x8 af[NG][QT][2];
    #pragma unroll
    for (int g = 0; g < NG; ++g) {
        #pragma unroll
        for (int t = 0; t < QT; ++t) {
            int sr = t * 16 + l15;
            int kk = (sr < GR) ? (sr >> 3) : 0;
            int rr = (sr < GR) ? (sr & 7) : 0;
            const short* qp = proj_bf + ((size_t)QP[g * CPG + kk] * NPc + brow0 + rr) * Dc + h * HDc;
            #pragma unroll
            for (int ks = 0; ks < 2; ++ks)
                af[g][t][ks] = *(const bf16x8*)(qp + ks * 32 + l4 * 8);
        }
    }
    __syncthreads();

    // ---- scores (pipelined over nt): S[m][j] = fw[c] * (q_m . k_j)
    {
        const short* Kb[NG];
        #pragma unroll
        for (int g = 0; g < NG; ++g)
            Kb[g] = proj_bf + ((size_t)KP[g] * NPc + (size_t)b * Sc) * Dc + h * HDc;

        float fwv[NG][QT];
        #pragma unroll
        for (int g = 0; g < NG; ++g)
            #pragma unroll
            for (int t = 0; t < QT; ++t) {
                int k = t * 2 + (l4 >> 1);
                fwv[g][t] = (k < CPG) ? fwl[CG[g * CPG + k]] : 0.f;
            }

        bf16x8 cur[NG][2];
        int nt = wv;
        {
            int j = nt * 16 + l15;
            #pragma unroll
            for (int g = 0; g < NG; ++g) {
                cur[g][0] = *(const bf16x8*)(Kb[g] + (size_t)j * Dc + l4 * 8);
                cur[g][1] = *(const bf16x8*)(Kb[g] + (size_t)j * Dc + 32 + l4 * 8);
            }
        }
        while (nt < 13) {
            const int ntn = nt + NW;
            bf16x8 nxt[NG][2];
            if (ntn < 13) {
                int j2 = ntn * 16 + l15;
                #pragma unroll
                for (int g = 0; g < NG; ++g) {
                    nxt[g][0] = *(const bf16x8*)(Kb[g] + (size_t)j2 * Dc + l4 * 8);
                    nxt[g][1] = *(const bf16x8*)(Kb[g] + (size_t)j2 * Dc + 32 + l4 * 8);
                }
            }
            const int j = nt * 16 + l15;
            const bool jv = (j < Sc);
            #pragma unroll
            for (int g = 0; g < NG; ++g) {
                #pragma unroll
                for (int t = 0; t < QT; ++t) {
                    f32x4 c = {};
                    c = mfma16(af[g][t][0], cur[g][0], c);
                    c = mfma16(af[g][t][1], cur[g][1], c);
                    int k = t * 2 + (l4 >> 1);
                    if (jv && k < CPG) {
                        int srb = g * GR + t * 16 + l4 * 4;
                        float f = fwv[g][t];
                        #pragma unroll
                        for (int i = 0; i < 4; ++i)
                            Sl[(srb + i) * SLD + j] = f2bf(c[i] * f);
                    }
                }
            }
            #pragma unroll
            for (int g = 0; g < NG; ++g) { cur[g][0] = nxt[g][0]; cur[g][1] = nxt[g][1]; }
            nt = ntn;
        }
    }
    __syncthreads();

    // ---- gate: Y[j][m] via MFMA(A=WT rows j, B=Sl rows m); e[m] reduce
    {
        float epart[MT2];
        #pragma unroll
        for (int mt = 0; mt < MT2; ++mt) epart[mt] = 0.f;

        for (int nt = wv; nt < 13; nt += NW) {
            const int jr = nt * 16 + l15;
            bf16x8 wfrag[7];
            #pragma unroll
            for (int ks = 0; ks < 7; ++ks)
                wfrag[ks] = *(const bf16x8*)(WT + (size_t)jr * 224 + ks * 32 + l4 * 8);
            f32x4 cg[MT2];
            #pragma unroll
            for (int mt = 0; mt < MT2; ++mt) cg[mt] = (f32x4){};
            #pragma unroll
            for (int ks = 0; ks < 7; ++ks) {
                #pragma unroll
                for (int mt = 0; mt < MT2; ++mt) {
                    bf16x8 bb = *(const bf16x8*)(Sl + (mt * 16 + l15) * SLD + ks * 32 + l4 * 8);
                    cg[mt] = mfma16(wfrag[ks], bb, cg[mt]);
                }
            }
            float4 b1 = *(const float4*)(bf1l + nt * 16 + l4 * 4);
            float4 w2 = *(const float4*)(wf2l + nt * 16 + l4 * 4);
            #pragma unroll
            for (int mt = 0; mt < MT2; ++mt) {
                float s = fmaxf(cg[mt][0] + b1.x, 0.f) * w2.x
                        + fmaxf(cg[mt][1] + b1.y, 0.f) * w2.y
                        + fmaxf(cg[mt][2] + b1.z, 0.f) * w2.z
                        + fmaxf(cg[mt][3] + b1.w, 0.f) * w2.w;
                s += __shfl_xor(s, 16, 64);
                s += __shfl_xor(s, 32, 64);
                epart[mt] += s;
            }
        }
        if (l4 == 0) {
            #pragma unroll
            for (int mt = 0; mt < MT2; ++mt)
                evw[wv * SROWS + mt * 16 + l15] = epart[mt];
        }
    }
    __syncthreads();

    // ================= wave-local tail: rows ra=wv, rb=wv+4 =================
    const int ra = wv, rb = wv + 4;

    // ---- channel softmax (redundant per wave, register result)
    float wchA[CH], wchB[CH];
    {
        float eA[CH], eB[CH];
        float mxA = -1e30f, mxB = -1e30f;
        #pragma unroll
        for (int c = 0; c < CH; ++c) {
            int m = M2S[c];
            float sA = 0.f, sB = 0.f;
            #pragma unroll
            for (int w = 0; w < NW; ++w) {
                sA += evw[w * SROWS + m + ra];
                sB += evw[w * SROWS + m + rb];
            }
            eA[c] = sA; eB[c] = sB;
            mxA = fmaxf(mxA, sA); mxB = fmaxf(mxB, sB);
        }
        float suA = 0.f, suB = 0.f;
        #pragma unroll
        for (int c = 0; c < CH; ++c) {
            eA[c] = __expf(eA[c] - mxA); suA += eA[c];
            eB[c] = __expf(eB[c] - mxB); suB += eB[c];
        }
        float ivA = 1.f / suA, ivB = 1.f / suB;
        #pragma unroll
        for (int c = 0; c < CH; ++c) { wchA[c] = eA[c] * ivA; wchB[c] = eB[c] * ivB; }
    }

    // ---- gated sum + scale + mask -> gbuf rows ra, rb (lane covers 4 j)
    if (lane < 50) {
        const int j4 = lane * 4;
        const float* mbase = mask + ((size_t)b * Sc + r0) * Sc;
        float aA[4] = {0.f, 0.f, 0.f, 0.f};
        float aB[4] = {0.f, 0.f, 0.f, 0.f};
        #pragma unroll
        for (int c = 0; c < CH; ++c) {
            bf16x4 sA = *(const bf16x4*)(Sl + (M2S[c] + ra) * SLD + j4);
            bf16x4 sB = *(const bf16x4*)(Sl + (M2S[c] + rb) * SLD + j4);
            float wA = wchA[c], wB = wchB[c];
            #pragma unroll
            for (int i = 0; i < 4; ++i) {
                aA[i] += wA * bf2f(sA[i]);
                aB[i] += wB * bf2f(sB[i]);
            }
        }
        float4 mA = *(const float4*)(mbase + (size_t)ra * Sc + j4);
        float4 mB = *(const float4*)(mbase + (size_t)rb * Sc + j4);
        float4 oA = make_float4(aA[0] * SCALE + mA.x, aA[1] * SCALE + mA.y,
                                aA[2] * SCALE + mA.z, aA[3] * SCALE + mA.w);
        float4 oB = make_float4(aB[0] * SCALE + mB.x, aB[1] * SCALE + mB.y,
                                aB[2] * SCALE + mB.z, aB[3] * SCALE + mB.w);
        *(float4*)(gbuf + ra * 200 + j4) = oA;
        *(float4*)(gbuf + rb * 200 + j4) = oB;
    }

    // ---- row softmax (rows ra, rb; wave-local)
    #pragma unroll
    for (int rr = 0; rr < 2; ++rr) {
        const int r = wv + rr * 4;
        float vals[4]; float mpart = -1e30f;
        #pragma unroll
        for (int t4 = 0; t4 < 4; ++t4) {
            int j = t4 * 64 + lane;
            vals[t4] = (j < Sc) ? gbuf[r * 200 + j] : -1e30f;
            mpart = fmaxf(mpart, vals[t4]);
        }
        #pragma unroll
        for (int off = 32; off >= 1; off >>= 1) mpart = fmaxf(mpart, __shfl_xor(mpart, off, 64));
        float spart = 0.f;
        #pragma unroll
        for (int t4 = 0; t4 < 4; ++t4) {
            int j = t4 * 64 + lane;
            if (j < Sc) {
                float exv = __expf(vals[t4] - mpart);
                gbuf[r * 200 + j] = exv;
                spart += exv;
            }
        }
        #pragma unroll
        for (int off = 32; off >= 1; off >>= 1) spart += __shfl_xor(spart, off, 64);
        float inv = 1.f / spart;
        #pragma unroll
        for (int t4 = 0; t4 < 4; ++t4) {
            int j = t4 * 64 + lane;
            if (j < Sc) gbuf[r * 200 + j] *= inv;
        }
    }

    // ---- PV: rows ra, rb share each V load
    {
        const float* vb = vf32 + ((size_t)b * Sc) * Dc + h * HDc + lane;
        const float* pA = gbuf + ra * 200;
        const float* pB = gbuf + rb * 200;
        float aA0 = 0.f, aA1 = 0.f, aA2 = 0.f, aA3 = 0.f;
        float aB0 = 0.f, aB1 = 0.f, aB2 = 0.f, aB3 = 0.f;
        for (int j = 0; j < Sc; j += 4) {
            float v0 = vb[(size_t)(j + 0) * Dc];
            float v1 = vb[(size_t)(j + 1) * Dc];
            float v2 = vb[(size_t)(j + 2) * Dc];
            float v3 = vb[(size_t)(j + 3) * Dc];
            aA0 += pA[j] * v0; aA1 += pA[j + 1] * v1; aA2 += pA[j + 2] * v2; aA3 += pA[j + 3] * v3;
            aB0 += pB[j] * v0; aB1 += pB[j + 1] * v1; aB2 += pB[j + 2] * v2; aB3 += pB[j + 3] * v3;
        }
        ctx_out[((size_t)(brow0 + ra)) * Dc + h * HDc + lane] = aA0 + aA1 + aA2 + aA3;
        ctx_out[((size_t)(brow0 + rb)) * Dc + h * HDc + lane] = aB0 + aB1 + aB2 + aB3;
    }
}

// ---------------------------------------------------------------------------
// Kernel 2 (v6): merged fused attention, 256 threads, XCD-balanced swizzle
// ---------------------------------------------------------------------------
__global__ __launch_bounds__(256, 3) void fused6(
    const short* __restrict__ proj_bf,
    const float* __restrict__ viv,
    const float* __restrict__ vhav,
    const float* __restrict__ fw9,
    const float* __restrict__ fw4,
    const float* __restrict__ mask,
    const short* __restrict__ WT,
    const float* __restrict__ bf1,
    const float* __restrict__ Wf2,
    float* __restrict__ ctx,
    float* __restrict__ ctxc)
{
    __shared__ __align__(16) short Sl[80 * 232];
    __shared__ float gbuf[8 * 200];
    __shared__ float evw[4 * 80];
    __shared__ float fwl[9];
    __shared__ float bf1l[224];
    __shared__ float wf2l[224];

    // XCD-balanced chunk swizzle: 25-block (b,h) chunks pinned per XCD,
    // 9ch/4ch chunks interleaved so each XCD gets 32 of each kind.
    const int d    = blockIdx.x;          // 0..12799
    const int xcd  = d & 7;
    const int slot = d >> 3;              // 0..1599
    const int chunk = (slot / 25) * 8 + xcd;   // 0..511
    const int pos   = slot % 25;
    const int bid   = chunk * 25 + pos;   // 0..12799

    if (bid < 6400) {
        fused_body<9, 3, 3, 2, 5>(bid, proj_bf, viv, fw9, mask, WT, bf1, Wf2, ctx,
                                  c_KP9, c_QP9, c_CG9, c_M2S9,
                                  Sl, gbuf, evw, fwl, bf1l, wf2l);
    } else {
        fused_body<4, 2, 2, 1, 2>(bid - 6400, proj_bf, vhav, fw4, mask, WT, bf1, Wf2, ctxc,
                                  c_KP4, c_QP4, c_CG4, c_M2S4,
                                  Sl, gbuf, evw, fwl, bf1l, wf2l);
    }
}

// ---------------------------------------------------------------------------
// Kernel 3: out = LayerNorm( A @ W + bias + resid ) * gamma + beta
// ---------------------------------------------------------------------------
__global__ __launch_bounds__(256) void out_ln_kernel(
    const float* __restrict__ Actx,
    const float* __restrict__ W,
    const float* __restrict__ bias,
    const float* __restrict__ resid,
    const float* __restrict__ gamma,
    const float* __restrict__ beta,
    float* __restrict__ out)
{
    const int m0 = blockIdx.x * 16;
    const int tid = threadIdx.x;

    __shared__ float As[16][256];
    __shared__ float ylds[16][256];

    for (int t = tid; t < 16 * 64; t += 256) {
        int r = t >> 6, k4 = t & 63;
        ((float4*)As[r])[k4] = ((const float4*)(Actx + (size_t)(m0 + r) * Dc))[k4];
    }
    __syncthreads();

    float acc[16];
    #pragma unroll
    for (int r = 0; r < 16; r++) acc[r] = 0.f;

    for (int k = 0; k < 256; k += 4) {
        float w0 = W[(size_t)(k    ) * Dc + tid];
        float w1 = W[(size_t)(k + 1) * Dc + tid];
        float w2 = W[(size_t)(k + 2) * Dc + tid];
        float w3 = W[(size_t)(k + 3) * Dc + tid];
        #pragma unroll
        for (int r = 0; r < 16; r++) {
            float4 a4 = ((float4*)As[r])[k >> 2];
            acc[r] += a4.x * w0 + a4.y * w1 + a4.z * w2 + a4.w * w3;
        }
    }

    const float bv = bias[tid];
    #pragma unroll
    for (int r = 0; r < 16; r++) {
        ylds[r][tid] = acc[r] + bv + resid[(size_t)(m0 + r) * Dc + tid];
    }
    __syncthreads();

    const int lane = tid & 63;
    const int wv   = tid >> 6;
    for (int r = wv * 4; r < wv * 4 + 4; r++) {
        float v4[4];
        float s = 0.f, s2 = 0.f;
        #pragma unroll
        for (int t4 = 0; t4 < 4; t4++) {
            float v = ylds[r][t4 * 64 + lane];
            v4[t4] = v;
            s += v;
            s2 += v * v;
        }
        #pragma unroll
        for (int off = 32; off >= 1; off >>= 1) {
            s  += __shfl_xor(s, off, 64);
            s2 += __shfl_xor(s2, off, 64);
        }
        float m   = s * (1.f / 256.f);
        float var = s2 * (1.f / 256.f) - m * m;
        float rstd = rsqrtf(var + 1e-12f);
        #pragma unroll
        for (int t4 = 0; t4 < 4; t4++) {
            int ccol = t4 * 64 + lane;
            out[(size_t)(m0 + r) * Dc + ccol] = (v4[t4] - m) * rstd * gamma[ccol] + beta[ccol];
        }
    }
}

// ---------------------------------------------------------------------------
// Launcher
// ---------------------------------------------------------------------------
extern "C" void kernel_launch(void* const* d_in, const int* in_sizes, int n_in,
                              void* d_out, int out_size, void* d_ws, size_t ws_size,
                              hipStream_t stream) {
    const float* X    = (const float*)d_in[0];
    const float* AT   = (const float*)d_in[1];
    const float* P    = (const float*)d_in[2];
    const float* HA   = (const float*)d_in[3];
    const float* mask = (const float*)d_in[4];
    const float* fw   = (const float*)d_in[5];
    const float* fwc  = (const float*)d_in[6];

    const float* Wq   = (const float*)d_in[7];
    const float* bq   = (const float*)d_in[8];
    const float* Wk   = (const float*)d_in[9];
    const float* bk   = (const float*)d_in[10];
    const float* Wv   = (const float*)d_in[11];
    const float* bv   = (const float*)d_in[12];
    const float* Wqp  = (const float*)d_in[13];
    const float* bqp  = (const float*)d_in[14];
    const float* Wkp  = (const float*)d_in[15];
    const float* bkp  = (const float*)d_in[16];
    const float* Waq  = (const float*)d_in[17];
    const float* baq  = (const float*)d_in[18];
    const float* Wak  = (const float*)d_in[19];
    const float* bak  = (const float*)d_in[20];
    const float* Wav  = (const float*)d_in[21];
    const float* bav  = (const float*)d_in[22];
    const float* Wqic = (const float*)d_in[23];
    const float* bqic = (const float*)d_in[24];
    const float* Wqci = (const float*)d_in[25];
    const float* bqci = (const float*)d_in[26];
    const float* Wqpc = (const float*)d_in[27];
    const float* bqpc = (const float*)d_in[28];
    const float* Wqcp = (const float*)d_in[29];
    const float* bqcp = (const float*)d_in[30];
    const float* Wf1  = (const float*)d_in[31];
    const float* bf1  = (const float*)d_in[32];
    const float* Wf2  = (const float*)d_in[33];
    const float* bf2  = (const float*)d_in[34];
    const float* Wd   = (const float*)d_in[35];
    const float* bd   = (const float*)d_in[36];
    const float* ln_g = (const float*)d_in[37];
    const float* ln_b = (const float*)d_in[38];
    const float* Wda  = (const float*)d_in[39];
    const float* bda  = (const float*)d_in[40];
    const float* lna_g= (const float*)d_in[41];
    const float* lna_b= (const float*)d_in[42];

    char* w = (char*)d_ws;
    short* proj_bf = (short*)w;  w += (size_t)NPROJ * NPc * Dc * sizeof(short);
    short* WTall   = (short*)w;  w += (size_t)NPROJ * Dc * Dc * sizeof(short);
    short* WTf1    = (short*)w;  w += (size_t)224 * 224 * sizeof(short);
    short* inb     = (short*)w;  w += (size_t)4 * NPc * Dc * sizeof(short);
    float* viv     = (float*)w;  w += (size_t)NPc * Dc * sizeof(float);
    float* vhav    = (float*)w;  w += (size_t)NPc * Dc * sizeof(float);
    float* ctx     = (float*)w;  w += (size_t)NPc * Dc * sizeof(float);
    float* ctxc    = (float*)w;  w += (size_t)NPc * Dc * sizeof(float);

    // input-tensor id per projection: 0=X 1=AT 2=P 3=HA
    const int aid[NPROJ] = {0,0,0,2,2,1,1,3,3,3,0,1,1,3,2};
    const float* Wmat[NPROJ] = {Wq, Wk, Wv, Wqp, Wkp, Waq, Wak, Waq, Wak, Wav, Wqic, Wqci, Wqcp, Wqcp, Wqpc};
    const float* bmat[NPROJ] = {bq, bk, bv, bqp, bkp, baq, bak, baq, bak, bav, bqic, bqci, bqcp, bqcp, bqpc};

    ProjArgsM pm;
    WList wl;
    for (int i = 0; i < NPROJ; i++) {
        pm.A[i]    = inb + (size_t)aid[i] * NPc * Dc;
        pm.bias[i] = bmat[i];
        pm.outf[i] = nullptr;
        wl.w[i]    = Wmat[i];
    }
    pm.outf[2] = viv;    // iv
    pm.outf[9] = vhav;   // hav

    // 0. casts
    cast_in<<<dim3(NPc * Dc / 4 / 256, 4), 256, 0, stream>>>(X, AT, P, HA, inb);
    cast_wt<<<dim3(16, NPROJ), 256, 0, stream>>>(wl, WTall);
    wf1t_kernel<<<(224 * 224 + 255) / 256, 256, 0, stream>>>(Wf1, WTf1);

    // 1. projections (MFMA, bf16 in/out + fp32 for V)
    proj_mfma<<<dim3(NPc / 64, NPROJ), 256, 0, stream>>>(pm, WTall, proj_bf);

    // 2. merged fused attention
    fused6<<<12800, 256, 0, stream>>>(proj_bf, viv, vhav, fw, fwc, mask, WTf1, bf1, Wf2, ctx, ctxc);

    // 3. output projections + residual + LayerNorm
    float* out0 = (float*)d_out;
    float* out1 = out0 + (size_t)NPc * Dc;
    out_ln_kernel<<<NPc / 16, 256, 0, stream>>>(ctx,  Wd,  bd,  X,  ln_g,  ln_b,  out0);
    out_ln_kernel<<<NPc / 16, 256, 0, stream>>>(ctxc, Wda, bda, HA, lna_g, lna_b, out1);
}

// Round 7
// 477.643 us; speedup vs baseline: 2.4892x; 1.2308x over previous
//
#include <hip/hip_runtime.h>
#include <cstddef>

typedef __attribute__((ext_vector_type(8))) short bf16x8;
typedef __attribute__((ext_vector_type(4))) short bf16x4;
typedef __attribute__((ext_vector_type(4))) float f32x4;

constexpr int Bc = 64;
constexpr int Sc = 200;
constexpr int Hc = 4;
constexpr int Dc = 256;
constexpr int HDc = 64;
constexpr int NPc = Bc * Sc;          // 12800 rows
constexpr int NPROJ = 15;
constexpr int NWT   = 17;             // 15 proj weights + Wd + Wda
constexpr float SCALE = 0.125f;       // 1/sqrt(64)

// proj indices
// 0 iq, 1 ik, 2 iv, 3 pq, 4 pk, 5 aq, 6 ak, 7 haq, 8 hak, 9 hav,
// 10 iqc, 11 ciq, 12 cqp, 13 cqp_a, 14 pqc

__constant__ int c_KP9[3]  = {1,6,4};                   // K proj per group
__constant__ int c_QP9[9]  = {0,11,3, 10,5,14, 0,12,3}; // Q proj per (g,k) slot
__constant__ int c_CG9[9]  = {0,3,6, 1,4,7, 2,5,8};     // slot -> channel
__constant__ int c_M2S9[9] = {0,24,48,8,32,56,16,40,64};// channel -> S row base
__constant__ int c_KP4[2]  = {8,4};
__constant__ int c_QP4[4]  = {7,14, 13,3};
__constant__ int c_CG4[4]  = {0,2, 1,3};
__constant__ int c_M2S4[4] = {0,16,8,24};

__device__ __forceinline__ short f2bf(float x) {
    union { float f; unsigned u; } v; v.f = x;
    unsigned r = v.u + 0x7FFFu + ((v.u >> 16) & 1u);
    return (short)(r >> 16);
}
__device__ __forceinline__ float bf2f(short x) {
    union { unsigned u; float f; } v; v.u = ((unsigned)(unsigned short)x) << 16;
    return v.f;
}
__device__ __forceinline__ f32x4 mfma16(bf16x8 a, bf16x8 b, f32x4 c) {
    return __builtin_amdgcn_mfma_f32_16x16x32_bf16(a, b, c, 0, 0, 0);
}

struct ProjArgsM {
    const short* A[NPROJ];      // bf16 input per projection
    const float* bias[NPROJ];
};
struct WList { const float* w[NWT]; };

// ---------------------------------------------------------------------------
// cast 4 input tensors fp32 -> bf16
// ---------------------------------------------------------------------------
__global__ void cast_in(const float* __restrict__ s0, const float* __restrict__ s1,
                        const float* __restrict__ s2, const float* __restrict__ s3,
                        short* __restrict__ dst) {
    const float* srcs[4] = {s0, s1, s2, s3};
    const float* src = srcs[blockIdx.y];
    short* d = dst + (size_t)blockIdx.y * NPc * Dc;
    int t = blockIdx.x * 256 + threadIdx.x;
    float4 v = ((const float4*)src)[t];
    bf16x4 o;
    o[0] = f2bf(v.x); o[1] = f2bf(v.y); o[2] = f2bf(v.z); o[3] = f2bf(v.w);
    *(bf16x4*)(d + (size_t)t * 4) = o;
}

// ---------------------------------------------------------------------------
// cast+transpose 17 weights: WT[p][n][k] = W[p][k][n]  (bf16)
// ---------------------------------------------------------------------------
__global__ void cast_wt(WList wl, short* __restrict__ dst) {
    __shared__ float tbuf[64][65];
    const int p = blockIdx.y;
    const int k0 = (blockIdx.x >> 2) * 64, n0 = (blockIdx.x & 3) * 64;
    const float* W = wl.w[p];
    short* d = dst + (size_t)p * Dc * Dc;
    const int tid = threadIdx.x;
    for (int i = tid; i < 64 * 64; i += 256) {
        int k = i >> 6, n = i & 63;
        tbuf[k][n] = W[(size_t)(k0 + k) * Dc + n0 + n];
    }
    __syncthreads();
    for (int i = tid; i < 64 * 64; i += 256) {
        int n = i >> 6, k = i & 63;
        d[(size_t)(n0 + n) * Dc + k0 + k] = f2bf(tbuf[k][n]);
    }
}

// ---------------------------------------------------------------------------
// Wf1 (200x200 f32) -> WT bf16 [224][224], WT[j][i] = Wf1[i][j], 0-pad
// ---------------------------------------------------------------------------
__global__ void wf1t_kernel(const float* __restrict__ Wf1, short* __restrict__ WT) {
    int t = blockIdx.x * 256 + threadIdx.x;
    if (t < 224 * 224) {
        int j = t / 224, i = t % 224;
        WT[t] = (i < Sc && j < Sc) ? f2bf(Wf1[(size_t)i * Sc + j]) : (short)0;
    }
}

// ---------------------------------------------------------------------------
// V transpose: proj_bf[p={2,9}] head strips -> vt[t][(b*4+h)][64][224] bf16
// grid 512: bid>>8 = tensor, bid&255 = (b,h)
// ---------------------------------------------------------------------------
__global__ __launch_bounds__(256) void vt_kernel(const short* __restrict__ proj_bf,
                                                 short* __restrict__ vt) {
    const int bid = blockIdx.x;
    const int t  = bid >> 8;
    const int bh = bid & 255;
    const int b = bh >> 2, h = bh & 3;
    const int p = t ? 9 : 2;
    const short* src = proj_bf + ((size_t)p * NPc + (size_t)b * Sc) * Dc + h * HDc;
    short* dst = vt + ((size_t)t * 256 + bh) * 64 * 224;
    __shared__ short tile[200][72];
    const int tid = threadIdx.x;
    for (int idx = tid; idx < 200 * 8; idx += 256) {
        int j = idx >> 3, c8 = idx & 7;
        *(bf16x8*)(&tile[j][c8 * 8]) = *(const bf16x8*)(src + (size_t)j * Dc + c8 * 8);
    }
    __syncthreads();
    for (int idx = tid; idx < 64 * 28; idx += 256) {
        int d = idx / 28, c8 = idx % 28;
        bf16x8 o;
        #pragma unroll
        for (int i = 0; i < 8; ++i) {
            int j = c8 * 8 + i;
            o[i] = (j < 200) ? tile[j][d] : (short)0;
        }
        *(bf16x8*)(dst + (size_t)d * 224 + c8 * 8) = o;
    }
}

// ---------------------------------------------------------------------------
// Kernel 1 (MFMA): all 15 projections. C[64 x 256] tile per block. bf16 out.
// ---------------------------------------------------------------------------
__global__ __launch_bounds__(256, 4) void proj_mfma(
    ProjArgsM args, const short* __restrict__ WTall, short* __restrict__ proj_bf)
{
    const int p  = blockIdx.y;
    const int m0 = blockIdx.x * 64;
    const short* __restrict__ A   = args.A[p];
    const short* __restrict__ WTp = WTall + (size_t)p * Dc * Dc;
    const float* __restrict__ bias = args.bias[p];
    short* __restrict__ ob = proj_bf + (size_t)p * NPc * Dc;

    __shared__ __align__(16) short As[64 * 264];
    const int tid = threadIdx.x;
    const int lane = tid & 63, w = tid >> 6;
    const int l15 = lane & 15, l4 = lane >> 4;

    for (int t = tid; t < 64 * 32; t += 256) {
        int r = t >> 5, c8 = t & 31;
        *(bf16x8*)(As + r * 264 + c8 * 8) = *(const bf16x8*)(A + (size_t)(m0 + r) * Dc + c8 * 8);
    }
    __syncthreads();

    f32x4 acc[4][4];
    #pragma unroll
    for (int mi = 0; mi < 4; ++mi)
        #pragma unroll
        for (int ni = 0; ni < 4; ++ni) acc[mi][ni] = (f32x4){};

    const int nb = w * 64;
    #pragma unroll
    for (int ks = 0; ks < 8; ++ks) {
        bf16x8 bfr[4];
        #pragma unroll
        for (int ni = 0; ni < 4; ++ni)
            bfr[ni] = *(const bf16x8*)(WTp + (size_t)(nb + ni * 16 + l15) * Dc + ks * 32 + l4 * 8);
        #pragma unroll
        for (int mi = 0; mi < 4; ++mi) {
            bf16x8 a = *(const bf16x8*)(As + (mi * 16 + l15) * 264 + ks * 32 + l4 * 8);
            #pragma unroll
            for (int ni = 0; ni < 4; ++ni)
                acc[mi][ni] = mfma16(a, bfr[ni], acc[mi][ni]);
        }
    }

    float bv[4];
    #pragma unroll
    for (int ni = 0; ni < 4; ++ni) bv[ni] = bias[nb + ni * 16 + l15];
    #pragma unroll
    for (int mi = 0; mi < 4; ++mi) {
        #pragma unroll
        for (int ni = 0; ni < 4; ++ni) {
            int n = nb + ni * 16 + l15;
            #pragma unroll
            for (int i = 0; i < 4; ++i) {
                int m = m0 + mi * 16 + l4 * 4 + i;
                ob[(size_t)m * Dc + n] = f2bf(acc[mi][ni][i] + bv[ni]);
            }
        }
    }
}

// ---------------------------------------------------------------------------
// fused body v7 (R = 8 rows per block, 4 waves, wave-local tail, PV via MFMA)
// ---------------------------------------------------------------------------
template <int CH, int NG, int CPG, int QT, int MT2>
__device__ void fused_body(
    int bid,
    const short* __restrict__ proj_bf,
    const short* __restrict__ vtb,       // [256][64][224] bf16 (per (b,h))
    const float* __restrict__ fw,
    const float* __restrict__ mask,
    const short* __restrict__ WT,
    const float* __restrict__ bf1,
    const float* __restrict__ Wf2,
    short* __restrict__ ctx_out,         // bf16 [NPc][256]
    const int* KP, const int* QP, const int* CG, const int* M2S,
    short* Sl, float* gbuf, float* evw, float* fwl,
    float* bf1l, float* wf2l)
{
    constexpr int GR    = CPG * 8;       // valid S rows per group
    constexpr int VROWS = NG * GR;       // total valid S rows
    constexpr int SROWS = MT2 * 16;
    constexpr int SLD   = 232;
    constexpr int NW    = 4;

    const int tid = threadIdx.x;
    const int rt  = bid % 25;
    const int h   = (bid / 25) & 3;
    const int b   = bid / 100;
    const int r0  = rt * 8;
    const int lane = tid & 63, wv = tid >> 6;   // wv 0..3
    const int l15 = lane & 15, l4 = lane >> 4;
    const int brow0 = b * Sc + r0;

    // ---- phase 0: zero only pad regions of Sl; stage bf1/Wf2; fw
    {
        bf16x8 z = {};
        if constexpr (SROWS > VROWS) {
            for (int t = tid; t < (SROWS - VROWS) * 28; t += 256) {
                int r = VROWS + t / 28, c8 = t % 28;
                *(bf16x8*)(Sl + r * SLD + c8 * 8) = z;
            }
        }
        for (int t = tid; t < VROWS * 3; t += 256) {
            int r = t / 3, c8 = t % 3;
            *(bf16x8*)(Sl + r * SLD + 200 + c8 * 8) = z;
        }
    }
    if (tid < 224) {
        bf1l[tid] = (tid < Sc) ? bf1[tid] : 0.f;
        wf2l[tid] = (tid < Sc) ? Wf2[tid] : 0.f;
    }
    if (tid < CH) fwl[tid] = fw[tid];

    // ---- preload Q A-fragments from global (registers)
    bf16x8 af[NG][QT][2];
    #pragma unroll
    for (int g = 0; g < NG; ++g) {
        #pragma unroll
        for (int t = 0; t < QT; ++t) {
            int sr = t * 16 + l15;
            int kk = (sr < GR) ? (sr >> 3) : 0;
            int rr = (sr < GR) ? (sr & 7) : 0;
            const short* qp = proj_bf + ((size_t)QP[g * CPG + kk] * NPc + brow0 + rr) * Dc + h * HDc;
            #pragma unroll
            for (int ks = 0; ks < 2; ++ks)
                af[g][t][ks] = *(const bf16x8*)(qp + ks * 32 + l4 * 8);
        }
    }
    __syncthreads();

    // ---- scores (pipelined over nt): S[m][j] = fw[c] * (q_m . k_j)
    {
        const short* Kb[NG];
        #pragma unroll
        for (int g = 0; g < NG; ++g)
            Kb[g] = proj_bf + ((size_t)KP[g] * NPc + (size_t)b * Sc) * Dc + h * HDc;

        float fwv[NG][QT];
        #pragma unroll
        for (int g = 0; g < NG; ++g)
            #pragma unroll
            for (int t = 0; t < QT; ++t) {
                int k = t * 2 + (l4 >> 1);
                fwv[g][t] = (k < CPG) ? fwl[CG[g * CPG + k]] : 0.f;
            }

        bf16x8 cur[NG][2];
        int nt = wv;
        {
            int j = nt * 16 + l15;
            #pragma unroll
            for (int g = 0; g < NG; ++g) {
                cur[g][0] = *(const bf16x8*)(Kb[g] + (size_t)j * Dc + l4 * 8);
                cur[g][1] = *(const bf16x8*)(Kb[g] + (size_t)j * Dc + 32 + l4 * 8);
            }
        }
        while (nt < 13) {
            const int ntn = nt + NW;
            bf16x8 nxt[NG][2];
            if (ntn < 13) {
                int j2 = ntn * 16 + l15;
                #pragma unroll
                for (int g = 0; g < NG; ++g) {
                    nxt[g][0] = *(const bf16x8*)(Kb[g] + (size_t)j2 * Dc + l4 * 8);
                    nxt[g][1] = *(const bf16x8*)(Kb[g] + (size_t)j2 * Dc + 32 + l4 * 8);
                }
            }
            const int j = nt * 16 + l15;
            const bool jv = (j < Sc);
            #pragma unroll
            for (int g = 0; g < NG; ++g) {
                #pragma unroll
                for (int t = 0; t < QT; ++t) {
                    f32x4 c = {};
                    c = mfma16(af[g][t][0], cur[g][0], c);
                    c = mfma16(af[g][t][1], cur[g][1], c);
                    int k = t * 2 + (l4 >> 1);
                    if (jv && k < CPG) {
                        int srb = g * GR + t * 16 + l4 * 4;
                        float f = fwv[g][t];
                        #pragma unroll
                        for (int i = 0; i < 4; ++i)
                            Sl[(srb + i) * SLD + j] = f2bf(c[i] * f);
                    }
                }
            }
            #pragma unroll
            for (int g = 0; g < NG; ++g) { cur[g][0] = nxt[g][0]; cur[g][1] = nxt[g][1]; }
            nt = ntn;
        }
    }
    __syncthreads();

    // ---- gate: Y[j][m] via MFMA(A=WT rows j, B=Sl rows m); e[m] reduce
    {
        float epart[MT2];
        #pragma unroll
        for (int mt = 0; mt < MT2; ++mt) epart[mt] = 0.f;

        for (int nt = wv; nt < 13; nt += NW) {
            const int jr = nt * 16 + l15;
            bf16x8 wfrag[7];
            #pragma unroll
            for (int ks = 0; ks < 7; ++ks)
                wfrag[ks] = *(const bf16x8*)(WT + (size_t)jr * 224 + ks * 32 + l4 * 8);
            f32x4 cg[MT2];
            #pragma unroll
            for (int mt = 0; mt < MT2; ++mt) cg[mt] = (f32x4){};
            #pragma unroll
            for (int ks = 0; ks < 7; ++ks) {
                #pragma unroll
                for (int mt = 0; mt < MT2; ++mt) {
                    bf16x8 bb = *(const bf16x8*)(Sl + (mt * 16 + l15) * SLD + ks * 32 + l4 * 8);
                    cg[mt] = mfma16(wfrag[ks], bb, cg[mt]);
                }
            }
            float4 b1 = *(const float4*)(bf1l + nt * 16 + l4 * 4);
            float4 w2 = *(const float4*)(wf2l + nt * 16 + l4 * 4);
            #pragma unroll
            for (int mt = 0; mt < MT2; ++mt) {
                float s = fmaxf(cg[mt][0] + b1.x, 0.f) * w2.x
                        + fmaxf(cg[mt][1] + b1.y, 0.f) * w2.y
                        + fmaxf(cg[mt][2] + b1.z, 0.f) * w2.z
                        + fmaxf(cg[mt][3] + b1.w, 0.f) * w2.w;
                s += __shfl_xor(s, 16, 64);
                s += __shfl_xor(s, 32, 64);
                epart[mt] += s;
            }
        }
        if (l4 == 0) {
            #pragma unroll
            for (int mt = 0; mt < MT2; ++mt)
                evw[wv * SROWS + mt * 16 + l15] = epart[mt];
        }
    }
    __syncthreads();

    // ================= wave-local tail: rows ra=wv, rb=wv+4 =================
    const int ra = wv, rb = wv + 4;

    // ---- channel softmax (redundant per wave, register result)
    float wchA[CH], wchB[CH];
    {
        float eA[CH], eB[CH];
        float mxA = -1e30f, mxB = -1e30f;
        #pragma unroll
        for (int c = 0; c < CH; ++c) {
            int m = M2S[c];
            float sA = 0.f, sB = 0.f;
            #pragma unroll
            for (int w = 0; w < NW; ++w) {
                sA += evw[w * SROWS + m + ra];
                sB += evw[w * SROWS + m + rb];
            }
            eA[c] = sA; eB[c] = sB;
            mxA = fmaxf(mxA, sA); mxB = fmaxf(mxB, sB);
        }
        float suA = 0.f, suB = 0.f;
        #pragma unroll
        for (int c = 0; c < CH; ++c) {
            eA[c] = __expf(eA[c] - mxA); suA += eA[c];
            eB[c] = __expf(eB[c] - mxB); suB += eB[c];
        }
        float ivA = 1.f / suA, ivB = 1.f / suB;
        #pragma unroll
        for (int c = 0; c < CH; ++c) { wchA[c] = eA[c] * ivA; wchB[c] = eB[c] * ivB; }
    }

    // ---- gated sum + scale + mask -> gbuf rows ra, rb (lane covers 4 j)
    if (lane < 50) {
        const int j4 = lane * 4;
        const float* mbase = mask + ((size_t)b * Sc + r0) * Sc;
        float aA[4] = {0.f, 0.f, 0.f, 0.f};
        float aB[4] = {0.f, 0.f, 0.f, 0.f};
        #pragma unroll
        for (int c = 0; c < CH; ++c) {
            bf16x4 sA = *(const bf16x4*)(Sl + (M2S[c] + ra) * SLD + j4);
            bf16x4 sB = *(const bf16x4*)(Sl + (M2S[c] + rb) * SLD + j4);
            float wA = wchA[c], wB = wchB[c];
            #pragma unroll
            for (int i = 0; i < 4; ++i) {
                aA[i] += wA * bf2f(sA[i]);
                aB[i] += wB * bf2f(sB[i]);
            }
        }
        float4 mA = *(const float4*)(mbase + (size_t)ra * Sc + j4);
        float4 mB = *(const float4*)(mbase + (size_t)rb * Sc + j4);
        float4 oA = make_float4(aA[0] * SCALE + mA.x, aA[1] * SCALE + mA.y,
                                aA[2] * SCALE + mA.z, aA[3] * SCALE + mA.w);
        float4 oB = make_float4(aB[0] * SCALE + mB.x, aB[1] * SCALE + mB.y,
                                aB[2] * SCALE + mB.z, aB[3] * SCALE + mB.w);
        *(float4*)(gbuf + ra * 200 + j4) = oA;
        *(float4*)(gbuf + rb * 200 + j4) = oB;
    }

    // ---- row softmax (rows ra, rb); write p bf16 into Sl rows 0..7 (wave-local)
    #pragma unroll
    for (int rr = 0; rr < 2; ++rr) {
        const int r = wv + rr * 4;
        float vals[4]; float mpart = -1e30f;
        #pragma unroll
        for (int t4 = 0; t4 < 4; ++t4) {
            int j = t4 * 64 + lane;
            vals[t4] = (j < Sc) ? gbuf[r * 200 + j] : -1e30f;
            mpart = fmaxf(mpart, vals[t4]);
        }
        #pragma unroll
        for (int off = 32; off >= 1; off >>= 1) mpart = fmaxf(mpart, __shfl_xor(mpart, off, 64));
        float pv[4]; float spart = 0.f;
        #pragma unroll
        for (int t4 = 0; t4 < 4; ++t4) {
            int j = t4 * 64 + lane;
            pv[t4] = (j < Sc) ? __expf(vals[t4] - mpart) : 0.f;
            spart += pv[t4];
        }
        #pragma unroll
        for (int off = 32; off >= 1; off >>= 1) spart += __shfl_xor(spart, off, 64);
        float inv = 1.f / spart;
        #pragma unroll
        for (int t4 = 0; t4 < 4; ++t4) {
            int j = t4 * 64 + lane;
            if (j < Sc) Sl[r * SLD + j] = f2bf(pv[t4] * inv);
        }
    }
    __syncthreads();

    // ---- PV via MFMA: A = p tile (Sl rows 0..15; 8 valid), B = Vt rows
    {
        const short* vb = vtb + ((size_t)(b * Hc + h) * 64) * 224;
        const int nb = wv * 16;
        f32x4 c0 = {}, c1 = {};
        #pragma unroll
        for (int ks = 0; ks < 7; ks += 2) {
            bf16x8 aa = *(const bf16x8*)(Sl + l15 * SLD + ks * 32 + l4 * 8);
            bf16x8 bb = *(const bf16x8*)(vb + (size_t)(nb + l15) * 224 + ks * 32 + l4 * 8);
            c0 = mfma16(aa, bb, c0);
            if (ks + 1 < 7) {
                bf16x8 aa1 = *(const bf16x8*)(Sl + l15 * SLD + (ks + 1) * 32 + l4 * 8);
                bf16x8 bb1 = *(const bf16x8*)(vb + (size_t)(nb + l15) * 224 + (ks + 1) * 32 + l4 * 8);
                c1 = mfma16(aa1, bb1, c1);
            }
        }
        if (l4 < 2) {
            #pragma unroll
            for (int i = 0; i < 4; ++i) {
                int row = l4 * 4 + i;
                ctx_out[((size_t)(brow0 + row)) * Dc + h * HDc + nb + l15] =
                    f2bf(c0[i] + c1[i]);
            }
        }
    }
}

// ---------------------------------------------------------------------------
// Kernel 2 (v7): merged fused attention, 256 threads, XCD-balanced swizzle
// ---------------------------------------------------------------------------
__global__ __launch_bounds__(256, 3) void fused7(
    const short* __restrict__ proj_bf,
    const short* __restrict__ vt,        // [2][256][64][224]
    const float* __restrict__ fw9,
    const float* __restrict__ fw4,
    const float* __restrict__ mask,
    const short* __restrict__ WT,
    const float* __restrict__ bf1,
    const float* __restrict__ Wf2,
    short* __restrict__ ctxb,
    short* __restrict__ ctxcb)
{
    __shared__ __align__(16) short Sl[80 * 232];
    __shared__ float gbuf[8 * 200];
    __shared__ float evw[4 * 80];
    __shared__ float fwl[9];
    __shared__ float bf1l[224];
    __shared__ float wf2l[224];

    const int d    = blockIdx.x;          // 0..12799
    const int xcd  = d & 7;
    const int slot = d >> 3;              // 0..1599
    const int chunk = (slot / 25) * 8 + xcd;
    const int pos   = slot % 25;
    const int bid   = chunk * 25 + pos;

    if (bid < 6400) {
        fused_body<9, 3, 3, 2, 5>(bid, proj_bf, vt, fw9, mask, WT, bf1, Wf2, ctxb,
                                  c_KP9, c_QP9, c_CG9, c_M2S9,
                                  Sl, gbuf, evw, fwl, bf1l, wf2l);
    } else {
        fused_body<4, 2, 2, 1, 2>(bid - 6400, proj_bf, vt + (size_t)256 * 64 * 224,
                                  fw4, mask, WT, bf1, Wf2, ctxcb,
                                  c_KP4, c_QP4, c_CG4, c_M2S4,
                                  Sl, gbuf, evw, fwl, bf1l, wf2l);
    }
}

// ---------------------------------------------------------------------------
// Kernel 3 (MFMA): out = LayerNorm( ctx(bf16) @ WdT + bias + resid ) * g + b
// 32 rows per block, 256 threads.
// ---------------------------------------------------------------------------
__global__ __launch_bounds__(256, 3) void out_ln_mfma(
    const short* __restrict__ Ab,     // bf16 [NPc][256]
    const short* __restrict__ WTp,    // bf16 [256][256] (n-major)
    const float* __restrict__ bias,
    const float* __restrict__ resid,
    const float* __restrict__ gamma,
    const float* __restrict__ beta,
    float* __restrict__ out)
{
    const int m0 = blockIdx.x * 32;
    __shared__ __align__(16) short As[32 * 264];
    __shared__ float ylds[32][257];
    const int tid = threadIdx.x;
    const int lane = tid & 63, wv = tid >> 6;
    const int l15 = lane & 15, l4 = lane >> 4;

    for (int t = tid; t < 32 * 32; t += 256) {
        int r = t >> 5, c8 = t & 31;
        *(bf16x8*)(As + r * 264 + c8 * 8) = *(const bf16x8*)(Ab + (size_t)(m0 + r) * Dc + c8 * 8);
    }
    __syncthreads();

    const int nb = wv * 64;
    f32x4 acc[2][4];
    #pragma unroll
    for (int mi = 0; mi < 2; ++mi)
        #pragma unroll
        for (int ni = 0; ni < 4; ++ni) acc[mi][ni] = (f32x4){};

    #pragma unroll
    for (int ks = 0; ks < 8; ++ks) {
        bf16x8 bfr[4];
        #pragma unroll
        for (int ni = 0; ni < 4; ++ni)
            bfr[ni] = *(const bf16x8*)(WTp + (size_t)(nb + ni * 16 + l15) * Dc + ks * 32 + l4 * 8);
        #pragma unroll
        for (int mi = 0; mi < 2; ++mi) {
            bf16x8 a = *(const bf16x8*)(As + (mi * 16 + l15) * 264 + ks * 32 + l4 * 8);
            #pragma unroll
            for (int ni = 0; ni < 4; ++ni)
                acc[mi][ni] = mfma16(a, bfr[ni], acc[mi][ni]);
        }
    }

    #pragma unroll
    for (int mi = 0; mi < 2; ++mi) {
        #pragma unroll
        for (int ni = 0; ni < 4; ++ni) {
            int n = nb + ni * 16 + l15;
            float bv = bias[n];
            #pragma unroll
            for (int i = 0; i < 4; ++i) {
                int row = mi * 16 + l4 * 4 + i;
                ylds[row][n] = acc[mi][ni][i] + bv + resid[(size_t)(m0 + row) * Dc + n];
            }
        }
    }
    __syncthreads();

    for (int r = wv * 8; r < wv * 8 + 8; ++r) {
        float v4[4];
        float s = 0.f, s2 = 0.f;
        #pragma unroll
        for (int t4 = 0; t4 < 4; ++t4) {
            float v = ylds[r][t4 * 64 + lane];
            v4[t4] = v;
            s += v; s2 += v * v;
        }
        #pragma unroll
        for (int off = 32; off >= 1; off >>= 1) {
            s  += __shfl_xor(s, off, 64);
            s2 += __shfl_xor(s2, off, 64);
        }
        float m   = s * (1.f / 256.f);
        float var = s2 * (1.f / 256.f) - m * m;
        float rstd = rsqrtf(var + 1e-12f);
        #pragma unroll
        for (int t4 = 0; t4 < 4; ++t4) {
            int ccol = t4 * 64 + lane;
            out[(size_t)(m0 + r) * Dc + ccol] = (v4[t4] - m) * rstd * gamma[ccol] + beta[ccol];
        }
    }
}

// ---------------------------------------------------------------------------
// Launcher
// ---------------------------------------------------------------------------
extern "C" void kernel_launch(void* const* d_in, const int* in_sizes, int n_in,
                              void* d_out, int out_size, void* d_ws, size_t ws_size,
                              hipStream_t stream) {
    const float* X    = (const float*)d_in[0];
    const float* AT   = (const float*)d_in[1];
    const float* P    = (const float*)d_in[2];
    const float* HA   = (const float*)d_in[3];
    const float* mask = (const float*)d_in[4];
    const float* fw   = (const float*)d_in[5];
    const float* fwc  = (const float*)d_in[6];

    const float* Wq   = (const float*)d_in[7];
    const float* bq   = (const float*)d_in[8];
    const float* Wk   = (const float*)d_in[9];
    const float* bk   = (const float*)d_in[10];
    const float* Wv   = (const float*)d_in[11];
    const float* bv   = (const float*)d_in[12];
    const float* Wqp  = (const float*)d_in[13];
    const float* bqp  = (const float*)d_in[14];
    const float* Wkp  = (const float*)d_in[15];
    const float* bkp  = (const float*)d_in[16];
    const float* Waq  = (const float*)d_in[17];
    const float* baq  = (const float*)d_in[18];
    const float* Wak  = (const float*)d_in[19];
    const float* bak  = (const float*)d_in[20];
    const float* Wav  = (const float*)d_in[21];
    const float* bav  = (const float*)d_in[22];
    const float* Wqic = (const float*)d_in[23];
    const float* bqic = (const float*)d_in[24];
    const float* Wqci = (const float*)d_in[25];
    const float* bqci = (const float*)d_in[26];
    const float* Wqpc = (const float*)d_in[27];
    const float* bqpc = (const float*)d_in[28];
    const float* Wqcp = (const float*)d_in[29];
    const float* bqcp = (const float*)d_in[30];
    const float* Wf1  = (const float*)d_in[31];
    const float* bf1  = (const float*)d_in[32];
    const float* Wf2  = (const float*)d_in[33];
    const float* bf2  = (const float*)d_in[34];
    const float* Wd   = (const float*)d_in[35];
    const float* bd   = (const float*)d_in[36];
    const float* ln_g = (const float*)d_in[37];
    const float* ln_b = (const float*)d_in[38];
    const float* Wda  = (const float*)d_in[39];
    const float* bda  = (const float*)d_in[40];
    const float* lna_g= (const float*)d_in[41];
    const float* lna_b= (const float*)d_in[42];

    char* w = (char*)d_ws;
    short* proj_bf = (short*)w;  w += (size_t)NPROJ * NPc * Dc * sizeof(short);
    short* WTall   = (short*)w;  w += (size_t)NWT * Dc * Dc * sizeof(short);
    short* WTf1    = (short*)w;  w += (size_t)224 * 224 * sizeof(short);
    short* inb     = (short*)w;  w += (size_t)4 * NPc * Dc * sizeof(short);
    short* vt      = (short*)w;  w += (size_t)2 * 256 * 64 * 224 * sizeof(short);
    short* ctxb    = (short*)w;  w += (size_t)NPc * Dc * sizeof(short);
    short* ctxcb   = (short*)w;  w += (size_t)NPc * Dc * sizeof(short);

    // input-tensor id per projection: 0=X 1=AT 2=P 3=HA
    const int aid[NPROJ] = {0,0,0,2,2,1,1,3,3,3,0,1,1,3,2};
    const float* Wmat[NWT] = {Wq, Wk, Wv, Wqp, Wkp, Waq, Wak, Waq, Wak, Wav,
                              Wqic, Wqci, Wqcp, Wqcp, Wqpc, Wd, Wda};
    const float* bmat[NPROJ] = {bq, bk, bv, bqp, bkp, baq, bak, baq, bak, bav,
                                bqic, bqci, bqcp, bqcp, bqpc};

    ProjArgsM pm;
    WList wl;
    for (int i = 0; i < NPROJ; i++) {
        pm.A[i]    = inb + (size_t)aid[i] * NPc * Dc;
        pm.bias[i] = bmat[i];
    }
    for (int i = 0; i < NWT; i++) wl.w[i] = Wmat[i];

    // 0. casts
    cast_in<<<dim3(NPc * Dc / 4 / 256, 4), 256, 0, stream>>>(X, AT, P, HA, inb);
    cast_wt<<<dim3(16, NWT), 256, 0, stream>>>(wl, WTall);
    wf1t_kernel<<<(224 * 224 + 255) / 256, 256, 0, stream>>>(Wf1, WTf1);

    // 1. projections (MFMA, bf16 in/out)
    proj_mfma<<<dim3(NPc / 64, NPROJ), 256, 0, stream>>>(pm, WTall, proj_bf);

    // 1b. V transpose (iv, hav) -> vt bf16
    vt_kernel<<<512, 256, 0, stream>>>(proj_bf, vt);

    // 2. merged fused attention (ctx out in bf16)
    fused7<<<12800, 256, 0, stream>>>(proj_bf, vt, fw, fwc, mask, WTf1, bf1, Wf2, ctxb, ctxcb);

    // 3. output projections + residual + LayerNorm (MFMA)
    float* out0 = (float*)d_out;
    float* out1 = out0 + (size_t)NPc * Dc;
    out_ln_mfma<<<NPc / 32, 256, 0, stream>>>(ctxb,  WTall + (size_t)15 * Dc * Dc, bd,
                                              X,  ln_g,  ln_b,  out0);
    out_ln_mfma<<<NPc / 32, 256, 0, stream>>>(ctxcb, WTall + (size_t)16 * Dc * Dc, bda,
                                              HA, lna_g, lna_b, out1);
}